// Round 2
// 564.280 us; speedup vs baseline: 1.0821x; 1.0821x over previous
//
#include <hip/hip_runtime.h>
#include <hip/hip_bf16.h>

// Problem constants (reference: B=1024, F=128, E=256, HEAD_NUM=8, d=32)
// Reference dtypes: ALL fp32 (inputs and output). bf16 internally.
#define B_SZ 1024
#define F_SZ 128
#define E_SZ 256
#define H_NUM 8
#define D_SZ 32

typedef __bf16 bf16x8 __attribute__((ext_vector_type(8)));
typedef float f32x4 __attribute__((ext_vector_type(4)));
typedef unsigned short u16x4 __attribute__((ext_vector_type(4)));

__device__ __forceinline__ bf16x8 frag_at(const __hip_bfloat16* p) {
  return *reinterpret_cast<const bf16x8*>(p);
}

__device__ __forceinline__ bf16x8 pack_bf16x8(float4 a, float4 b) {
  bf16x8 r;
  r[0] = (__bf16)a.x; r[1] = (__bf16)a.y; r[2] = (__bf16)a.z; r[3] = (__bf16)a.w;
  r[4] = (__bf16)b.x; r[5] = (__bf16)b.y; r[6] = (__bf16)b.z; r[7] = (__bf16)b.w;
  return r;
}

// ---------------------------------------------------------------------------
// Prep: transpose the four fp32 E x E weights into bf16 WT[n][e] (n-major).
// ---------------------------------------------------------------------------
__global__ void transpose_weights(const float* __restrict__ W0,
                                  const float* __restrict__ W1,
                                  const float* __restrict__ W2,
                                  const float* __restrict__ W3,
                                  __hip_bfloat16* __restrict__ WT) {
  __shared__ float tile[64][65];
  const int wsel = blockIdx.x >> 4;
  const float* W = wsel == 0 ? W0 : wsel == 1 ? W1 : wsel == 2 ? W2 : W3;
  __hip_bfloat16* T = WT + wsel * (E_SZ * E_SZ);
  const int t = blockIdx.x & 15;
  const int tr = (t >> 2) * 64, tc = (t & 3) * 64;
  for (int k = 0; k < 16; ++k) {
    int fl = k * 256 + threadIdx.x;
    int lr = fl >> 6, lc = fl & 63;
    tile[lr][lc] = W[(tr + lr) * E_SZ + tc + lc];
  }
  __syncthreads();
  for (int k = 0; k < 16; ++k) {
    int fl = k * 256 + threadIdx.x;
    int lr = fl >> 6, lc = fl & 63;
    T[(tc + lr) * E_SZ + tr + lc] = __float2bfloat16(tile[lc][lr]);
  }
}

// ---------------------------------------------------------------------------
// Kernel A v3: LDS-tiled QKVR projection GEMM.
// Changes vs v2:
//  (1) XCD-aware bijective swizzle: all 8 ntb-blocks of a batch land on the
//      SAME XCD (xcd = bid&7 owns batches xcd*128..xcd*128+127), so the
//      batch's 128 KB X-tile is fetched from HBM once and L2-served 7x.
//  (2) Coalesced epilogue: C-tiles staged per-wave into the (free after the
//      K-loop) main-loop LDS at stride 72 (144 B rows: 16B-aligned, rows
//      offset by 4 banks), then stored as bf16x8 -> each 8-lane group writes
//      one full aligned 128 B line. V is transposed in LDS so VT rows are
//      written contiguously too. Eliminates partial-sector HBM writes.
// ---------------------------------------------------------------------------
#define STRA 72   // LDS row stride (64 + 8) for main loop AND epilogue staging
__global__ __launch_bounds__(256, 1)
void gemm_qkvr(const float* __restrict__ X,
               const __hip_bfloat16* __restrict__ WT,
               __hip_bfloat16* __restrict__ Qo,
               __hip_bfloat16* __restrict__ Ko,
               __hip_bfloat16* __restrict__ Ro,
               __hip_bfloat16* __restrict__ VT) {
  __shared__ __align__(16) __hip_bfloat16 smem[2 * 128 * STRA];  // 36864 B
  __hip_bfloat16* const As = smem;
  __hip_bfloat16* const Bs = smem + 128 * STRA;

  const int tid  = threadIdx.x;
  const int wave = tid >> 6;
  const int lane = tid & 63;
  const int quad = lane >> 4;
  const int l16  = lane & 15;
  const int wm   = wave >> 1;            // 0..1 row half of the wave grid
  const int wn   = wave & 1;             // 0..1 col half

  // XCD swizzle: dispatch round-robins blockIdx across 8 XCDs (bid%8).
  // Map so XCD x processes batches [x*128, (x+1)*128), all 8 ntb together.
  const int xcd = blockIdx.x & 7;
  const int idx = blockIdx.x >> 3;       // 0..1023 slot within this XCD
  const int bm  = xcd * 128 + (idx >> 3);
  const int ntb = idx & 7;

  const int mat  = ntb >> 1;             // 0=Q 1=K 2=V 3=R
  const int colbase = (ntb & 1) * 128;   // col offset within mat
  const float* Xb = X + (size_t)bm * (F_SZ * E_SZ);
  const __hip_bfloat16* Wb = WT + mat * (E_SZ * E_SZ) + colbase * E_SZ;

  // per-thread staging slice: 4 chunks of 8 elems; chunk ch=i*256+tid:
  // row r = ch>>3 (8 chunks/row), chunk-in-row c = ch&7.
  float4 la0[4], la1[4];
  uint4  lb[4];

  auto load_tiles = [&](int kt) {
    const int k0 = kt * 64;
    #pragma unroll
    for (int i = 0; i < 4; ++i) {
      int ch = i * 256 + tid;
      int r = ch >> 3, c = ch & 7;
      const float* sa = Xb + r * E_SZ + k0 + c * 8;
      la0[i] = *reinterpret_cast<const float4*>(sa);
      la1[i] = *reinterpret_cast<const float4*>(sa + 4);
      lb[i]  = *reinterpret_cast<const uint4*>(Wb + r * E_SZ + k0 + c * 8);
    }
  };
  auto write_tiles = [&]() {
    #pragma unroll
    for (int i = 0; i < 4; ++i) {
      int ch = i * 256 + tid;
      int r = ch >> 3, c = ch & 7;
      bf16x8 av = pack_bf16x8(la0[i], la1[i]);
      *reinterpret_cast<bf16x8*>(&As[r * STRA + c * 8]) = av;
      *reinterpret_cast<uint4*>(&Bs[r * STRA + c * 8]) = lb[i];
    }
  };

  f32x4 acc[4][4];
  #pragma unroll
  for (int mt = 0; mt < 4; ++mt)
    #pragma unroll
    for (int nt = 0; nt < 4; ++nt) acc[mt][nt] = f32x4{0.f, 0.f, 0.f, 0.f};

  load_tiles(0);
  #pragma unroll
  for (int kt = 0; kt < 4; ++kt) {
    write_tiles();
    __syncthreads();
    if (kt < 3) load_tiles(kt + 1);   // in flight during compute
    #pragma unroll
    for (int kk = 0; kk < 2; ++kk) {
      const int ko = kk * 32 + quad * 8;
      bf16x8 af[4], bfr[4];
      #pragma unroll
      for (int mt = 0; mt < 4; ++mt)
        af[mt] = frag_at(&As[(wm * 64 + mt * 16 + l16) * STRA + ko]);
      #pragma unroll
      for (int nt = 0; nt < 4; ++nt)
        bfr[nt] = frag_at(&Bs[(wn * 64 + nt * 16 + l16) * STRA + ko]);
      #pragma unroll
      for (int mt = 0; mt < 4; ++mt)
        #pragma unroll
        for (int nt = 0; nt < 4; ++nt)
          acc[mt][nt] = __builtin_amdgcn_mfma_f32_16x16x32_bf16(
              af[mt], bfr[nt], acc[mt][nt], 0, 0, 0);
    }
    __syncthreads();
  }

  // ---- epilogue v3: stage per-wave 64x64 C-tile in LDS, store full lines.
  // C/D fragment layout: row = quad*4+reg, col = l16 (within 16x16 tile).
  // Per-wave staging region: 64 rows x STRA(72) bf16 = 9216 B; 4 waves fill
  // the 36864 B main-loop buffer exactly (free after final __syncthreads).
  __hip_bfloat16* const Ls = smem + wave * (64 * STRA);
  const int rsub = lane >> 3;        // 0..7: row-in-pass
  const int csub = (lane & 7) * 8;   // 0..56: 8-elem chunk

  if (mat != 2) {
    // Stage row-major: Ls[r][c] = C[r][c].
    #pragma unroll
    for (int mt = 0; mt < 4; ++mt)
      #pragma unroll
      for (int nt = 0; nt < 4; ++nt)
        #pragma unroll
        for (int reg = 0; reg < 4; ++reg)
          Ls[(mt * 16 + quad * 4 + reg) * STRA + nt * 16 + l16] =
              __float2bfloat16(acc[mt][nt][reg]);
    __syncthreads();
    __hip_bfloat16* O = (mat == 0) ? Qo : (mat == 1) ? Ko : Ro;
    #pragma unroll
    for (int pass = 0; pass < 8; ++pass) {
      const int rt = pass * 8 + rsub;                       // 0..63
      bf16x8 v = *reinterpret_cast<const bf16x8*>(&Ls[rt * STRA + csub]);
      const size_t m = (size_t)bm * F_SZ + wm * 64 + rt;
      *reinterpret_cast<bf16x8*>(
          &O[m * E_SZ + colbase + wn * 64 + csub]) = v;     // 128 B / 8 lanes
    }
  } else {
    // Stage transposed: Ls[c][r] = C[r][c]  (c = head*32+d index, r = f).
    // Note (h*32+d) == global col c, so VT row index is bm*256 + c.
    #pragma unroll
    for (int mt = 0; mt < 4; ++mt)
      #pragma unroll
      for (int nt = 0; nt < 4; ++nt) {
        u16x4 pk;
        #pragma unroll
        for (int reg = 0; reg < 4; ++reg) {
          __hip_bfloat16 bv = __float2bfloat16(acc[mt][nt][reg]);
          pk[reg] = *reinterpret_cast<unsigned short*>(&bv);
        }
        *reinterpret_cast<u16x4*>(
            &Ls[(nt * 16 + l16) * STRA + mt * 16 + quad * 4]) = pk;
      }
    __syncthreads();
    #pragma unroll
    for (int pass = 0; pass < 8; ++pass) {
      const int ct = pass * 8 + rsub;                       // 0..63 (h,d)
      bf16x8 v = *reinterpret_cast<const bf16x8*>(&Ls[ct * STRA + csub]);
      const int c = colbase + wn * 64 + ct;
      *reinterpret_cast<bf16x8*>(
          &VT[((size_t)bm * 256 + c) * F_SZ + wm * 64 + csub]) = v;
    }
  }
}

// ---------------------------------------------------------------------------
// Kernel B: attention. One block per (b,h); 8192 blocks x 256 thr (4 waves).
// Zero barriers; P via wave-private LDS slice.
// v3 change: XCD swizzle so all 8 heads of a batch share one XCD's L2
// (heads h,h+1 share 128 B lines in Qo/Ko/Ro; also same XCD gemm wrote from).
// ---------------------------------------------------------------------------
#define STRP2 144
__global__ __launch_bounds__(256, 1)
void attn(const __hip_bfloat16* __restrict__ Qo,
          const __hip_bfloat16* __restrict__ Ko,
          const __hip_bfloat16* __restrict__ Ro,
          const __hip_bfloat16* __restrict__ VT,
          float* __restrict__ out) {
  __shared__ __align__(16) __hip_bfloat16 Ps[4][32 * STRP2];  // 36864 B

  const int tid  = threadIdx.x;
  const int wave = tid >> 6;
  const int lane = tid & 63;
  const int quad = lane >> 4;
  const int l16  = lane & 15;

  const int xcd = blockIdx.x & 7;
  const int idx = blockIdx.x >> 3;
  const int b   = xcd * 128 + (idx >> 3);
  const int h   = idx & 7;

  const size_t rowbase = (size_t)b * F_SZ;
  const int hcol = h * D_SZ;
  const int fw   = wave * 32;
  __hip_bfloat16* Pw = &Ps[wave][0];
  const __hip_bfloat16* VTh = VT + ((size_t)b * H_NUM + h) * (D_SZ * F_SZ);

  // ---- S = Q_h K_h^T (K=32 -> one MFMA per 16x16 tile)
  bf16x8 bk[8];
  #pragma unroll
  for (int nt = 0; nt < 8; ++nt)
    bk[nt] = frag_at(Ko + (rowbase + nt * 16 + l16) * E_SZ + hcol + quad * 8);

  f32x4 s[2][8];
  #pragma unroll
  for (int mt = 0; mt < 2; ++mt) {
    bf16x8 aq = frag_at(Qo + (rowbase + fw + mt * 16 + l16) * E_SZ + hcol + quad * 8);
    #pragma unroll
    for (int nt = 0; nt < 8; ++nt)
      s[mt][nt] = __builtin_amdgcn_mfma_f32_16x16x32_bf16(
          aq, bk[nt], f32x4{0.f, 0.f, 0.f, 0.f}, 0, 0, 0);
  }

  // ---- row softmax + P -> own LDS slice (C-layout -> A-layout)
  #pragma unroll
  for (int mt = 0; mt < 2; ++mt)
    #pragma unroll
    for (int reg = 0; reg < 4; ++reg) {
      float m = s[mt][0][reg];
      #pragma unroll
      for (int nt = 1; nt < 8; ++nt) m = fmaxf(m, s[mt][nt][reg]);
      #pragma unroll
      for (int off = 8; off >= 1; off >>= 1) m = fmaxf(m, __shfl_xor(m, off));
      float sum = 0.f;
      #pragma unroll
      for (int nt = 0; nt < 8; ++nt) {
        float e = __expf(s[mt][nt][reg] - m);
        s[mt][nt][reg] = e;
        sum += e;
      }
      #pragma unroll
      for (int off = 8; off >= 1; off >>= 1) sum += __shfl_xor(sum, off);
      float inv = 1.f / sum;
      int r = mt * 16 + quad * 4 + reg;
      #pragma unroll
      for (int nt = 0; nt < 8; ++nt)
        Pw[r * STRP2 + nt * 16 + l16] = __float2bfloat16(s[mt][nt][reg] * inv);
    }

  // ---- O = P V (K=128 -> 4 k-steps); V^T B-frags direct from global
  f32x4 o[2][2];
  o[0][0] = f32x4{0.f,0.f,0.f,0.f}; o[0][1] = f32x4{0.f,0.f,0.f,0.f};
  o[1][0] = f32x4{0.f,0.f,0.f,0.f}; o[1][1] = f32x4{0.f,0.f,0.f,0.f};
  #pragma unroll
  for (int ks = 0; ks < 4; ++ks) {
    bf16x8 bv0 = frag_at(VTh + (l16) * F_SZ      + ks * 32 + quad * 8);
    bf16x8 bv1 = frag_at(VTh + (16 + l16) * F_SZ + ks * 32 + quad * 8);
    #pragma unroll
    for (int mt = 0; mt < 2; ++mt) {
      bf16x8 ap = *reinterpret_cast<const bf16x8*>(
          Pw + (mt * 16 + l16) * STRP2 + ks * 32 + quad * 8);
      o[mt][0] = __builtin_amdgcn_mfma_f32_16x16x32_bf16(ap, bv0, o[mt][0], 0, 0, 0);
      o[mt][1] = __builtin_amdgcn_mfma_f32_16x16x32_bf16(ap, bv1, o[mt][1], 0, 0, 0);
    }
  }

  // ---- epilogue: + residual, relu (NaN-propagating), fp32 store
  #pragma unroll
  for (int mt = 0; mt < 2; ++mt)
    #pragma unroll
    for (int nt = 0; nt < 2; ++nt)
      #pragma unroll
      for (int reg = 0; reg < 4; ++reg) {
        int f = fw + mt * 16 + quad * 4 + reg;
        size_t idx2 = (rowbase + f) * E_SZ + hcol + nt * 16 + l16;
        float v = o[mt][nt][reg] + (float)Ro[idx2];
        out[idx2] = (v < 0.f) ? 0.f : v;
      }
}

// ---------------------------------------------------------------------------
extern "C" void kernel_launch(void* const* d_in, const int* in_sizes, int n_in,
                              void* d_out, int out_size, void* d_ws, size_t ws_size,
                              hipStream_t stream) {
  const float* X  = (const float*)d_in[0];
  const float* Wq = (const float*)d_in[1];
  const float* Wk = (const float*)d_in[2];
  const float* Wv = (const float*)d_in[3];
  const float* Wr = (const float*)d_in[4];
  float* out = (float*)d_out;

  char* ws = (char*)d_ws;
  const size_t WT_BYTES  = (size_t)4 * E_SZ * E_SZ * 2;           // 512 KB
  const size_t MAT_BYTES = (size_t)B_SZ * F_SZ * E_SZ * 2;        // 64 MB

  __hip_bfloat16* WT = (__hip_bfloat16*)ws;
  __hip_bfloat16* Qo = (__hip_bfloat16*)(ws + WT_BYTES);
  __hip_bfloat16* Ko = (__hip_bfloat16*)(ws + WT_BYTES + MAT_BYTES);
  __hip_bfloat16* Ro = (__hip_bfloat16*)(ws + WT_BYTES + 2 * MAT_BYTES);
  __hip_bfloat16* VT = (__hip_bfloat16*)(ws + WT_BYTES + 3 * MAT_BYTES);

  (void)hipGetLastError();  // clear stale error state
  transpose_weights<<<64, 256, 0, stream>>>(Wq, Wk, Wv, Wr, WT);
  gemm_qkvr<<<B_SZ * 8, 256, 0, stream>>>(X, WT, Qo, Ko, Ro, VT);
  attn<<<B_SZ * H_NUM, 256, 0, stream>>>(Qo, Ko, Ro, VT, out);

  // Launch-failure exfiltration (no-op when launches succeed).
  hipError_t err = hipGetLastError();
  if (err != hipSuccess) {
    hipMemsetAsync(d_out, 0x7F, 1024, stream);
  }
}

// Round 3
// 428.837 us; speedup vs baseline: 1.4238x; 1.3158x over previous
//
#include <hip/hip_runtime.h>
#include <hip/hip_bf16.h>

// Problem constants (reference: B=1024, F=128, E=256, HEAD_NUM=8, d=32)
// Reference dtypes: ALL fp32 (inputs and output). bf16 internally.
#define B_SZ 1024
#define F_SZ 128
#define E_SZ 256
#define H_NUM 8
#define D_SZ 32

typedef __bf16 bf16x8 __attribute__((ext_vector_type(8)));
typedef float f32x4 __attribute__((ext_vector_type(4)));
typedef unsigned short u16x4 __attribute__((ext_vector_type(4)));

__device__ __forceinline__ bf16x8 frag_at(const __hip_bfloat16* p) {
  return *reinterpret_cast<const bf16x8*>(p);
}

__device__ __forceinline__ bf16x8 pack_bf16x8(float4 a, float4 b) {
  bf16x8 r;
  r[0] = (__bf16)a.x; r[1] = (__bf16)a.y; r[2] = (__bf16)a.z; r[3] = (__bf16)a.w;
  r[4] = (__bf16)b.x; r[5] = (__bf16)b.y; r[6] = (__bf16)b.z; r[7] = (__bf16)b.w;
  return r;
}

// ---------------------------------------------------------------------------
// Prep: transpose the four fp32 E x E weights into bf16 WT[n][e] (n-major).
// ---------------------------------------------------------------------------
__global__ void transpose_weights(const float* __restrict__ W0,
                                  const float* __restrict__ W1,
                                  const float* __restrict__ W2,
                                  const float* __restrict__ W3,
                                  __hip_bfloat16* __restrict__ WT) {
  __shared__ float tile[64][65];
  const int wsel = blockIdx.x >> 4;
  const float* W = wsel == 0 ? W0 : wsel == 1 ? W1 : wsel == 2 ? W2 : W3;
  __hip_bfloat16* T = WT + wsel * (E_SZ * E_SZ);
  const int t = blockIdx.x & 15;
  const int tr = (t >> 2) * 64, tc = (t & 3) * 64;
  for (int k = 0; k < 16; ++k) {
    int fl = k * 256 + threadIdx.x;
    int lr = fl >> 6, lc = fl & 63;
    tile[lr][lc] = W[(tr + lr) * E_SZ + tc + lc];
  }
  __syncthreads();
  for (int k = 0; k < 16; ++k) {
    int fl = k * 256 + threadIdx.x;
    int lr = fl >> 6, lc = fl & 63;
    T[(tc + lr) * E_SZ + tr + lc] = __float2bfloat16(tile[lc][lr]);
  }
}

// ---------------------------------------------------------------------------
// v4: fully fused per-batch megakernel. One block per batch b; 512 thr = 8
// waves. X staged once in LDS (bf16). Per head h:
//   Phase P: wave w => mat (w>>1: Q/K/V/R), row-half (w&1). Output 128x32
//            head slice. A-frags from Xs (LDS), B-frags from WT (global,
//            L2-resident). Q/K/R row-major LDS; V transposed [d][f].
//   Phase S: wave w owns S rows w*16 (16x128, K=32 -> 8 MFMA); in-register
//            softmax (verified pattern); P -> wave-private LDS slice.
//   Phase PV: O(16x32) = P(16x128) Vt(32x128)^T, 4 k-steps; epilogue adds
//            Rs, relu, stores fp32 out. One head writes complete 128-B
//            lines of out (32 fp32 = head slice) => no partial-line wb.
// 2 barriers per head. No intermediate HBM traffic at all.
// ---------------------------------------------------------------------------
#define XST 264   // Xs stride (256 + 8): row = 528 B -> 2-way banks max
#define QST 40    // Qs/Ks/Rs stride (32 + 8): row = 80 B
#define VST 136   // Vt stride (128 + 8): row = 272 B
#define PST 136   // Ps stride (128 + 8)

// LDS element offsets (bf16), all 16-B aligned
#define XS_OFF 0
#define QS_OFF (128 * XST)                    // 33792
#define KS_OFF (QS_OFF + 128 * QST)          // 38912
#define RS_OFF (KS_OFF + 128 * QST)          // 44032
#define VT_OFF (RS_OFF + 128 * QST)          // 49152
#define PS_OFF (VT_OFF + 32 * VST)           // 53504
#define SMEM_ELEMS (PS_OFF + 8 * 16 * PST)   // 70912 -> 141824 B

__global__ __launch_bounds__(512, 2)
void fused_attn(const float* __restrict__ X,
                const __hip_bfloat16* __restrict__ WT,
                float* __restrict__ out) {
  __shared__ __align__(16) __hip_bfloat16 smem[SMEM_ELEMS];
  __hip_bfloat16* const Xs = smem + XS_OFF;
  __hip_bfloat16* const Qs = smem + QS_OFF;
  __hip_bfloat16* const Ks = smem + KS_OFF;
  __hip_bfloat16* const Rs = smem + RS_OFF;
  __hip_bfloat16* const Vt = smem + VT_OFF;
  __hip_bfloat16* const Ps = smem + PS_OFF;

  const int tid  = threadIdx.x;
  const int wave = tid >> 6;          // 0..7
  const int lane = tid & 63;
  const int quad = lane >> 4;
  const int l16  = lane & 15;
  const int b    = blockIdx.x;

  // ---- prologue: stage X_b (fp32 -> bf16) into LDS, coalesced
  const float* Xb = X + (size_t)b * (F_SZ * E_SZ);
  #pragma unroll
  for (int i = 0; i < 8; ++i) {
    int ch = i * 512 + tid;           // 0..4095 chunks of 8 floats
    int r = ch >> 5, c = ch & 31;     // 32 chunks per 256-wide row
    const float* sa = Xb + r * E_SZ + c * 8;
    float4 a0 = *reinterpret_cast<const float4*>(sa);
    float4 a1 = *reinterpret_cast<const float4*>(sa + 4);
    *reinterpret_cast<bf16x8*>(&Xs[r * XST + c * 8]) = pack_bf16x8(a0, a1);
  }
  __syncthreads();

  const int pmat = wave >> 1;         // 0=Q 1=K 2=V 3=R
  const int prh  = wave & 1;          // row half (64 rows)
  const __hip_bfloat16* Wmat = WT + pmat * (E_SZ * E_SZ);
  __hip_bfloat16* const Pw = Ps + wave * 16 * PST;

  for (int h = 0; h < H_NUM; ++h) {
    // ================= Phase P: QKVR head-slice projection =================
    {
      const __hip_bfloat16* Wh = Wmat + (h * D_SZ) * E_SZ;
      f32x4 acc[4][2];
      #pragma unroll
      for (int mt = 0; mt < 4; ++mt) {
        acc[mt][0] = f32x4{0.f, 0.f, 0.f, 0.f};
        acc[mt][1] = f32x4{0.f, 0.f, 0.f, 0.f};
      }
      #pragma unroll
      for (int ks = 0; ks < 8; ++ks) {
        const int ko = ks * 32 + quad * 8;
        bf16x8 b0 = frag_at(Wh + l16 * E_SZ + ko);          // cols h*32+0..15
        bf16x8 b1 = frag_at(Wh + (16 + l16) * E_SZ + ko);   // cols h*32+16..31
        #pragma unroll
        for (int mt = 0; mt < 4; ++mt) {
          bf16x8 af = frag_at(&Xs[(prh * 64 + mt * 16 + l16) * XST + ko]);
          acc[mt][0] = __builtin_amdgcn_mfma_f32_16x16x32_bf16(af, b0, acc[mt][0], 0, 0, 0);
          acc[mt][1] = __builtin_amdgcn_mfma_f32_16x16x32_bf16(af, b1, acc[mt][1], 0, 0, 0);
        }
      }
      // store slices to LDS.  C/D layout: row = quad*4+reg, col = l16.
      if (pmat == 2) {
        // V transposed: Vt[d][f]
        #pragma unroll
        for (int mt = 0; mt < 4; ++mt)
          #pragma unroll
          for (int nt = 0; nt < 2; ++nt) {
            u16x4 pk;
            #pragma unroll
            for (int reg = 0; reg < 4; ++reg) {
              __hip_bfloat16 bv = __float2bfloat16(acc[mt][nt][reg]);
              pk[reg] = *reinterpret_cast<unsigned short*>(&bv);
            }
            *reinterpret_cast<u16x4*>(
                &Vt[(nt * 16 + l16) * VST + prh * 64 + mt * 16 + quad * 4]) = pk;
          }
      } else {
        __hip_bfloat16* T = (pmat == 0) ? Qs : (pmat == 1) ? Ks : Rs;
        #pragma unroll
        for (int mt = 0; mt < 4; ++mt)
          #pragma unroll
          for (int nt = 0; nt < 2; ++nt)
            #pragma unroll
            for (int reg = 0; reg < 4; ++reg)
              T[(prh * 64 + mt * 16 + quad * 4 + reg) * QST + nt * 16 + l16] =
                  __float2bfloat16(acc[mt][nt][reg]);
      }
    }
    __syncthreads();

    // ================= Phase S: S = Q K^T, softmax, P -> LDS ===============
    {
      bf16x8 aq = frag_at(&Qs[(wave * 16 + l16) * QST + quad * 8]);
      f32x4 s[8];
      #pragma unroll
      for (int nt = 0; nt < 8; ++nt) {
        bf16x8 bk = frag_at(&Ks[(nt * 16 + l16) * QST + quad * 8]);
        s[nt] = __builtin_amdgcn_mfma_f32_16x16x32_bf16(
            aq, bk, f32x4{0.f, 0.f, 0.f, 0.f}, 0, 0, 0);
      }
      #pragma unroll
      for (int reg = 0; reg < 4; ++reg) {
        float m = s[0][reg];
        #pragma unroll
        for (int nt = 1; nt < 8; ++nt) m = fmaxf(m, s[nt][reg]);
        #pragma unroll
        for (int off = 8; off >= 1; off >>= 1) m = fmaxf(m, __shfl_xor(m, off));
        float sum = 0.f;
        #pragma unroll
        for (int nt = 0; nt < 8; ++nt) {
          float e = __expf(s[nt][reg] - m);
          s[nt][reg] = e;
          sum += e;
        }
        #pragma unroll
        for (int off = 8; off >= 1; off >>= 1) sum += __shfl_xor(sum, off);
        float inv = 1.f / sum;
        int r = quad * 4 + reg;
        #pragma unroll
        for (int nt = 0; nt < 8; ++nt)
          Pw[r * PST + nt * 16 + l16] = __float2bfloat16(s[nt][reg] * inv);
      }
    }

    // ================= Phase PV + fused residual/relu epilogue =============
    {
      f32x4 o[2];
      o[0] = f32x4{0.f, 0.f, 0.f, 0.f};
      o[1] = f32x4{0.f, 0.f, 0.f, 0.f};
      #pragma unroll
      for (int ks = 0; ks < 4; ++ks) {
        const int ko = ks * 32 + quad * 8;
        bf16x8 ap  = *reinterpret_cast<const bf16x8*>(Pw + l16 * PST + ko);
        bf16x8 bv0 = frag_at(&Vt[l16 * VST + ko]);
        bf16x8 bv1 = frag_at(&Vt[(16 + l16) * VST + ko]);
        o[0] = __builtin_amdgcn_mfma_f32_16x16x32_bf16(ap, bv0, o[0], 0, 0, 0);
        o[1] = __builtin_amdgcn_mfma_f32_16x16x32_bf16(ap, bv1, o[1], 0, 0, 0);
      }
      #pragma unroll
      for (int nt = 0; nt < 2; ++nt)
        #pragma unroll
        for (int reg = 0; reg < 4; ++reg) {
          int f = wave * 16 + quad * 4 + reg;
          float rv = (float)Rs[f * QST + nt * 16 + l16];
          float v = o[nt][reg] + rv;
          size_t idx = ((size_t)b * F_SZ + f) * E_SZ + h * D_SZ + nt * 16 + l16;
          out[idx] = (v < 0.f) ? 0.f : v;
        }
    }
    __syncthreads();
  }
}

// ---------------------------------------------------------------------------
extern "C" void kernel_launch(void* const* d_in, const int* in_sizes, int n_in,
                              void* d_out, int out_size, void* d_ws, size_t ws_size,
                              hipStream_t stream) {
  const float* X  = (const float*)d_in[0];
  const float* Wq = (const float*)d_in[1];
  const float* Wk = (const float*)d_in[2];
  const float* Wv = (const float*)d_in[3];
  const float* Wr = (const float*)d_in[4];
  float* out = (float*)d_out;

  __hip_bfloat16* WT = (__hip_bfloat16*)d_ws;   // 4*256*256*2 = 512 KB

  (void)hipGetLastError();  // clear stale error state
  transpose_weights<<<64, 256, 0, stream>>>(Wq, Wk, Wv, Wr, WT);
  fused_attn<<<B_SZ, 512, 0, stream>>>(X, WT, out);

  // Launch-failure exfiltration (no-op when launches succeed).
  hipError_t err = hipGetLastError();
  if (err != hipSuccess) {
    hipMemsetAsync(d_out, 0x7F, 1024, stream);
  }
}